// Round 16
// baseline (301.852 us; speedup 1.0000x reference)
//
#include <hip/hip_runtime.h>
#include <math.h>

#define DIN 128
#define DH  32
#define H1  8
#define H2  2
#define GNUM 64
#define DOUT 10
#define NEG_SLOPE 0.2f
#define SCAN_B 512

typedef __attribute__((ext_vector_type(8))) short sv8;
typedef __attribute__((ext_vector_type(4))) short sv4;
typedef __attribute__((ext_vector_type(4))) float fv4;

static __device__ __forceinline__ unsigned short f2bf(float f) {
    unsigned int u = __float_as_uint(f);
    unsigned int r = (u + 0x7fffu + ((u >> 16) & 1u)) >> 16;
    return (unsigned short)r;
}
static __device__ __forceinline__ float bf2f(unsigned short h) {
    return __uint_as_float(((unsigned int)h) << 16);
}

// ---------------------------------------------------------------------------
// Prep: zero deg, transpose+split W1/W2 (small)
// ---------------------------------------------------------------------------
__global__ void k_prep(const float* __restrict__ W1l, const float* __restrict__ W1r,
                       const float* __restrict__ W2l, const float* __restrict__ W2r,
                       short* __restrict__ B1th, short* __restrict__ B1tl,
                       short* __restrict__ B2th, short* __restrict__ B2tl,
                       int* __restrict__ zbase, int nz) {
    int id = blockIdx.x * blockDim.x + threadIdx.x;
    if (id < nz) zbase[id] = 0;        // deg[N+1]
    const int T1 = 512 * 128;
    const int T2 = 128 * 256;
    if (id < T1) {
        int n = id / 128, k = id - n * 128;
        float v = (n < 256) ? W1l[(size_t)k * 256 + n] : W1r[(size_t)k * 256 + (n - 256)];
        unsigned short h = f2bf(v);
        B1th[id] = (short)h;
        B1tl[id] = (short)f2bf(v - bf2f(h));
    } else if (id < T1 + T2) {
        int id2 = id - T1;
        int n = id2 / 256, k = id2 - n * 256;
        float v = (n < 64) ? W2l[(size_t)k * 64 + n] : W2r[(size_t)k * 64 + (n - 64)];
        unsigned short h = f2bf(v);
        B2th[id2] = (short)h;
        B2tl[id2] = (short)f2bf(v - bf2f(h));
    }
}

// ---------------------------------------------------------------------------
// CSR build
// ---------------------------------------------------------------------------
__global__ void k_deg(const int* __restrict__ dst, int* __restrict__ deg, int E, int n) {
    int i = blockIdx.x * blockDim.x + threadIdx.x;
    if (i < E) {
        atomicAdd(&deg[dst[i]], 1);
    } else if (i < E + n) {
        atomicAdd(&deg[i - E], 1);   // self loop
    }
}

__global__ __launch_bounds__(SCAN_B)
void k_scan_partial(const int* __restrict__ deg, int* __restrict__ bsum, int n) {
    int i = blockIdx.x * SCAN_B + threadIdx.x;
    int v = (i < n) ? deg[i] : 0;
    #pragma unroll
    for (int m = 32; m >= 1; m >>= 1) v += __shfl_xor(v, m);
    __shared__ int red[SCAN_B / 64];
    if ((threadIdx.x & 63) == 0) red[threadIdx.x >> 6] = v;
    __syncthreads();
    if (threadIdx.x == 0) {
        int s = 0;
        #pragma unroll
        for (int k = 0; k < SCAN_B / 64; ++k) s += red[k];
        bsum[blockIdx.x] = s;
    }
}

// scan_apply with inlined block-prefix (nb <= 64)
__global__ __launch_bounds__(SCAN_B)
void k_scan_apply(int* __restrict__ deg, int* __restrict__ cursor,
                  const int* __restrict__ bsum, int n, int nb) {
    __shared__ int buf[SCAN_B];
    __shared__ int pfx_s, tot_s;
    const int t = threadIdx.x, b = blockIdx.x;
    if (t < 64) {
        int v = (t < nb) ? bsum[t] : 0;
        int incl = v;
        #pragma unroll
        for (int o = 1; o < 64; o <<= 1) {
            int w = __shfl_up(incl, o);
            if (t >= o) incl += w;
        }
        int pfx = (b == 0) ? 0 : __shfl(incl, b - 1);
        int tot = __shfl(incl, nb - 1);
        if (t == 0) { pfx_s = pfx; tot_s = tot; }
    }
    int i = b * SCAN_B + t;
    int v = (i < n) ? deg[i] : 0;
    buf[t] = v;
    __syncthreads();
    for (int o = 1; o < SCAN_B; o <<= 1) {
        int a = (t >= o) ? buf[t - o] : 0;
        __syncthreads();
        buf[t] += a;
        __syncthreads();
    }
    int excl = buf[t] - v + pfx_s;
    if (i < n) { deg[i] = excl; cursor[i] = excl; }
    if (b == 0 && t == 0) deg[n] = tot_s;
}

__global__ void k_scatter(const int* __restrict__ src, const int* __restrict__ dst,
                          int* __restrict__ cursor, int* __restrict__ csr_src, int E, int n) {
    int i = blockIdx.x * blockDim.x + threadIdx.x;
    if (i < E) {
        int d = dst[i];
        int pos = atomicAdd(&cursor[d], 1);
        csr_src[pos] = src[i];
    } else if (i < E + n) {
        int v = i - E;
        int pos = atomicAdd(&cursor[v], 1);
        csr_src[pos] = v;   // self loop
    }
}

// ---------------------------------------------------------------------------
// Layer-1 GEMM: 64x128 tile (1876 blocks -> 7.3/CU), 4 waves of 32x64
// (acc[2][4]), A f32 -> bf16 hi/lo staged via LDS (10.2 KB). 3 products.
// Epilogue in 32x64 slices (8.7 KB) -> LDS = 10.2 KB.
// ---------------------------------------------------------------------------
__global__ __launch_bounds__(256)
void k_gemm1(const float* __restrict__ A,
             const short* __restrict__ Bth, const short* __restrict__ Btl,
             unsigned short* __restrict__ Cl, float* __restrict__ Cr,
             int M, int K, int Ntot, int NL) {
    __shared__ union {
        struct { short hi[64 * 40]; short lo[64 * 40]; } a;   // 10240 B
        float c[32 * 68];                                      // 8704 B
    } sm;
    const int tid = threadIdx.x;
    const int lane = tid & 63;
    const int wid = tid >> 6;
    const int wm = wid & 1, wn = wid >> 1;
    const int m0 = blockIdx.x * 64;
    const int n0 = blockIdx.y * 128;
    const int l15 = lane & 15, q = lane >> 4;

    fv4 acc[2][4] = {};

    for (int kk = 0; kk < K; kk += 32) {
        __syncthreads();
        // stage A tile: 64 rows x 32 k (f32 -> bf16 hi/lo), coalesced
        #pragma unroll
        for (int i = 0; i < 2; ++i) {
            int idx = tid + i * 256;      // 512 float4 slots
            int row = idx >> 3;
            int qq  = idx & 7;
            int mg  = m0 + row;
            float4 v = make_float4(0.f, 0.f, 0.f, 0.f);
            if (mg < M) v = *(const float4*)(A + (size_t)mg * K + kk + qq * 4);
            unsigned short hx = f2bf(v.x), hy = f2bf(v.y), hz = f2bf(v.z), hw = f2bf(v.w);
            sv4 hi = { (short)hx, (short)hy, (short)hz, (short)hw };
            sv4 lo = { (short)f2bf(v.x - bf2f(hx)), (short)f2bf(v.y - bf2f(hy)),
                       (short)f2bf(v.z - bf2f(hz)), (short)f2bf(v.w - bf2f(hw)) };
            *(sv4*)&sm.a.hi[row * 40 + qq * 4] = hi;
            *(sv4*)&sm.a.lo[row * 40 + qq * 4] = lo;
        }
        __syncthreads();

        sv8 bh[4], bl[4];
        #pragma unroll
        for (int fn = 0; fn < 4; ++fn) {
            int ng = n0 + wn * 64 + fn * 16 + l15;
            bh[fn] = *(const sv8*)(Bth + (size_t)ng * K + kk + q * 8);
            bl[fn] = *(const sv8*)(Btl + (size_t)ng * K + kk + q * 8);
        }
        #pragma unroll
        for (int fm = 0; fm < 2; ++fm) {
            int rl = wm * 32 + fm * 16 + l15;
            sv8 ah = *(const sv8*)&sm.a.hi[rl * 40 + q * 8];
            sv8 al = *(const sv8*)&sm.a.lo[rl * 40 + q * 8];
            #pragma unroll
            for (int fn = 0; fn < 4; ++fn) {
                acc[fm][fn] = __builtin_amdgcn_mfma_f32_16x16x32_bf16(ah, bh[fn], acc[fm][fn], 0, 0, 0);
                acc[fm][fn] = __builtin_amdgcn_mfma_f32_16x16x32_bf16(ah, bl[fn], acc[fm][fn], 0, 0, 0);
                acc[fm][fn] = __builtin_amdgcn_mfma_f32_16x16x32_bf16(al, bh[fn], acc[fm][fn], 0, 0, 0);
            }
        }
    }

    // epilogue: 4 slices (row-half s x col-half cn), 32x64 each
    const int NR = Ntot - NL;
    #pragma unroll
    for (int s = 0; s < 2; ++s) {
        #pragma unroll
        for (int cn = 0; cn < 2; ++cn) {
            __syncthreads();
            if (wm == s && wn == cn) {
                #pragma unroll
                for (int fm = 0; fm < 2; ++fm)
                    #pragma unroll
                    for (int fn = 0; fn < 4; ++fn)
                        #pragma unroll
                        for (int r = 0; r < 4; ++r)
                            sm.c[(fm * 16 + q * 4 + r) * 68 + fn * 16 + l15] = acc[fm][fn][r];
            }
            __syncthreads();
            int lr = tid >> 3;              // 0..31
            int grow = m0 + s * 32 + lr;
            if (grow < M) {
                #pragma unroll
                for (int k4 = 0; k4 < 2; ++k4) {
                    int jj = (tid & 7) + k4 * 8;    // 0..15 float4 index
                    float4 vv = *(float4*)&sm.c[lr * 68 + jj * 4];
                    int gcol = n0 + cn * 64 + jj * 4;
                    if (gcol < NL) {
                        ushort4 uu;
                        uu.x = f2bf(vv.x); uu.y = f2bf(vv.y);
                        uu.z = f2bf(vv.z); uu.w = f2bf(vv.w);
                        *(ushort4*)(Cl + (size_t)grow * NL + gcol) = uu;
                    } else {
                        *(float4*)(Cr + (size_t)grow * NR + (gcol - NL)) = vv;
                    }
                }
            }
        }
    }
}

// ---------------------------------------------------------------------------
// Layer-2 GEMM: 32x128 tile (938 blocks), 4 waves of 32x32 (acc[2][2]),
// A bf16 (h1b), 2 products. A-tile LDS 2.6 KB; epilogue 32x64 slices.
// ---------------------------------------------------------------------------
__global__ __launch_bounds__(256)
void k_gemm_bf(const unsigned short* __restrict__ A, const short* __restrict__ Bth,
               const short* __restrict__ Btl,
               unsigned short* __restrict__ Cl, float* __restrict__ Cr,
               int M, int K, int Ntot, int NL) {
    __shared__ union {
        short a[32 * 40];       // 2560 B
        float c[32 * 68];       // 8704 B
    } sm;
    const int tid = threadIdx.x;
    const int lane = tid & 63;
    const int wn = tid >> 6;            // wave col quarter (0..3)
    const int m0 = blockIdx.x * 32;
    const int n0 = 0;
    const int l15 = lane & 15, q = lane >> 4;

    fv4 acc[2][2] = {};

    for (int kk = 0; kk < K; kk += 32) {
        __syncthreads();
        // stage A tile: 32 rows x 32 k bf16 (128 sv8 chunks)
        if (tid < 128) {
            int row = tid >> 2, qq = tid & 3;
            int mg = m0 + row;
            sv8 v = { 0, 0, 0, 0, 0, 0, 0, 0 };
            if (mg < M) v = *(const sv8*)(A + (size_t)mg * K + kk + qq * 8);
            *(sv8*)&sm.a[row * 40 + qq * 8] = v;
        }
        __syncthreads();

        sv8 bh[2], bl[2];
        #pragma unroll
        for (int fn = 0; fn < 2; ++fn) {
            int ng = n0 + wn * 32 + fn * 16 + l15;
            bh[fn] = *(const sv8*)(Bth + (size_t)ng * K + kk + q * 8);
            bl[fn] = *(const sv8*)(Btl + (size_t)ng * K + kk + q * 8);
        }
        #pragma unroll
        for (int fm = 0; fm < 2; ++fm) {
            int rl = fm * 16 + l15;
            sv8 ah = *(const sv8*)&sm.a[rl * 40 + q * 8];
            #pragma unroll
            for (int fn = 0; fn < 2; ++fn) {
                acc[fm][fn] = __builtin_amdgcn_mfma_f32_16x16x32_bf16(ah, bh[fn], acc[fm][fn], 0, 0, 0);
                acc[fm][fn] = __builtin_amdgcn_mfma_f32_16x16x32_bf16(ah, bl[fn], acc[fm][fn], 0, 0, 0);
            }
        }
    }

    // epilogue: 2 col slices of 32x64 (waves wn=2cn, 2cn+1 own each slice)
    const int NR = Ntot - NL;
    #pragma unroll
    for (int cn = 0; cn < 2; ++cn) {
        __syncthreads();
        if ((wn >> 1) == cn) {
            #pragma unroll
            for (int fm = 0; fm < 2; ++fm)
                #pragma unroll
                for (int fn = 0; fn < 2; ++fn)
                    #pragma unroll
                    for (int r = 0; r < 4; ++r)
                        sm.c[(fm * 16 + q * 4 + r) * 68 + (wn & 1) * 32 + fn * 16 + l15] = acc[fm][fn][r];
        }
        __syncthreads();
        int lr = tid >> 3;              // 0..31
        int grow = m0 + lr;
        if (grow < M) {
            #pragma unroll
            for (int k4 = 0; k4 < 2; ++k4) {
                int jj = (tid & 7) + k4 * 8;
                float4 vv = *(float4*)&sm.c[lr * 68 + jj * 4];
                int gcol = n0 + cn * 64 + jj * 4;
                if (gcol < NL) {
                    ushort4 uu;
                    uu.x = f2bf(vv.x); uu.y = f2bf(vv.y);
                    uu.z = f2bf(vv.z); uu.w = f2bf(vv.w);
                    *(ushort4*)(Cl + (size_t)grow * NL + gcol) = uu;
                } else {
                    *(float4*)(Cr + (size_t)grow * NR + (gcol - NL)) = vv;
                }
            }
        }
    }
}

// ---------------------------------------------------------------------------
// Layer-1 edge pass: one wave per block; lane li owns 8 ch, half = edge slot.
// ---------------------------------------------------------------------------
__global__ __launch_bounds__(64)
void k_edge1(const unsigned short* __restrict__ XLB, const float* __restrict__ XR,
             const int* __restrict__ offs, const int* __restrict__ csr,
             const float* __restrict__ att, const float* __restrict__ bias,
             unsigned short* __restrict__ out, int n) {
    const int lane = threadIdx.x;
    const int v = blockIdx.x;
    const int li = lane & 31;
    const int half = lane >> 5;
    float av[8], xr[8];
    #pragma unroll
    for (int k = 0; k < 8; ++k) av[k] = att[li * 8 + k];
    #pragma unroll
    for (int k = 0; k < 8; ++k) xr[k] = XR[(size_t)v * 256 + li * 8 + k];
    const uint4* XL4 = (const uint4*)XLB;   // row = 32 uint4 (256 bf16)
    float z = 0.f;
    float acc[8] = {};
    const int e0 = offs[v], e1 = offs[v + 1];
    for (int j0 = e0; j0 < e1; j0 += 4) {
        #pragma unroll
        for (int p = 0; p < 2; ++p) {
            int j = j0 + p * 2 + half;
            bool valid = (j < e1);
            int jj = valid ? j : (e1 - 1);
            int src = csr[jj];
            uint4 u = XL4[(size_t)src * 32 + li];
            float f[8];
            f[0] = __uint_as_float(u.x << 16);  f[1] = __uint_as_float(u.x & 0xffff0000u);
            f[2] = __uint_as_float(u.y << 16);  f[3] = __uint_as_float(u.y & 0xffff0000u);
            f[4] = __uint_as_float(u.z << 16);  f[5] = __uint_as_float(u.z & 0xffff0000u);
            f[6] = __uint_as_float(u.w << 16);  f[7] = __uint_as_float(u.w & 0xffff0000u);
            float s1 = 0.f, s2 = 0.f;
            #pragma unroll
            for (int k = 0; k < 8; ++k) {
                float t = f[k] + xr[k];
                s1 = fmaf(t, av[k], s1);
                s2 = fmaf(fabsf(t), av[k], s2);
            }
            float s = fmaf(0.6f, s1, 0.4f * s2);
            s += __shfl_xor(s, 1);
            s += __shfl_xor(s, 2);
            float w = valid ? __expf(s) : 0.f;
            z += w;
            #pragma unroll
            for (int k = 0; k < 8; ++k) acc[k] = fmaf(w, f[k], acc[k]);
        }
    }
    z += __shfl_xor(z, 32);
    #pragma unroll
    for (int k = 0; k < 8; ++k) acc[k] += __shfl_xor(acc[k], 32);
    if (half == 0) {
        const float rz = 1.f / z;
        unsigned int o[4];
        #pragma unroll
        for (int k2 = 0; k2 < 4; ++k2) {
            float lo = fmaf(acc[k2 * 2 + 0], rz, bias[li * 8 + k2 * 2 + 0]);
            float hi = fmaf(acc[k2 * 2 + 1], rz, bias[li * 8 + k2 * 2 + 1]);
            lo = (lo > 0.f) ? lo : (__expf(lo) - 1.f);
            hi = (hi > 0.f) ? hi : (__expf(hi) - 1.f);
            o[k2] = (unsigned int)f2bf(lo) | ((unsigned int)f2bf(hi) << 16);
        }
        uint4 ov = { o[0], o[1], o[2], o[3] };
        *(uint4*)(out + (size_t)v * 256 + li * 8) = ov;
    }
}

// ---------------------------------------------------------------------------
// Layer-2 edge pass: one wave per block; li owns 8 ch, slot = lane>>3.
// ---------------------------------------------------------------------------
__global__ __launch_bounds__(64)
void k_edge2(const unsigned short* __restrict__ XLB, const float* __restrict__ XR,
             const int* __restrict__ offs, const int* __restrict__ csr,
             const float* __restrict__ att, const float* __restrict__ bias,
             float* __restrict__ out, int n) {
    const int lane = threadIdx.x;
    const int v = blockIdx.x;
    const int li = lane & 7;
    const int slot = lane >> 3;
    float av[8], xr[8];
    #pragma unroll
    for (int k = 0; k < 8; ++k) av[k] = att[li * 8 + k];
    #pragma unroll
    for (int k = 0; k < 8; ++k) xr[k] = XR[(size_t)v * 64 + li * 8 + k];
    const uint4* XL4 = (const uint4*)XLB;   // row = 8 uint4 (64 bf16)
    float z = 0.f;
    float acc[8] = {};
    const int e0 = offs[v], e1 = offs[v + 1];
    for (int j0 = e0; j0 < e1; j0 += 8) {
        int j = j0 + slot;
        bool valid = (j < e1);
        int jj = valid ? j : (e1 - 1);
        int src = csr[jj];
        uint4 u = XL4[(size_t)src * 8 + li];
        float f[8];
        f[0] = __uint_as_float(u.x << 16);  f[1] = __uint_as_float(u.x & 0xffff0000u);
        f[2] = __uint_as_float(u.y << 16);  f[3] = __uint_as_float(u.y & 0xffff0000u);
        f[4] = __uint_as_float(u.z << 16);  f[5] = __uint_as_float(u.z & 0xffff0000u);
        f[6] = __uint_as_float(u.w << 16);  f[7] = __uint_as_float(u.w & 0xffff0000u);
        float s1 = 0.f, s2 = 0.f;
        #pragma unroll
        for (int k = 0; k < 8; ++k) {
            float t = f[k] + xr[k];
            s1 = fmaf(t, av[k], s1);
            s2 = fmaf(fabsf(t), av[k], s2);
        }
        float s = fmaf(0.6f, s1, 0.4f * s2);
        s += __shfl_xor(s, 1);
        s += __shfl_xor(s, 2);
        float w = valid ? __expf(s) : 0.f;
        z += w;
        #pragma unroll
        for (int k = 0; k < 8; ++k) acc[k] = fmaf(w, f[k], acc[k]);
    }
    z += __shfl_xor(z, 8);  z += __shfl_xor(z, 16);  z += __shfl_xor(z, 32);
    #pragma unroll
    for (int k = 0; k < 8; ++k) {
        acc[k] += __shfl_xor(acc[k], 8);
        acc[k] += __shfl_xor(acc[k], 16);
        acc[k] += __shfl_xor(acc[k], 32);
    }
    if (slot == 0) {
        const float rz = 1.f / z;
        float o[8];
        #pragma unroll
        for (int k = 0; k < 8; ++k)
            o[k] = fmaf(acc[k], rz, bias[li * 8 + k]);
        float4 o0 = { o[0], o[1], o[2], o[3] };
        float4 o1 = { o[4], o[5], o[6], o[7] };
        *(float4*)(out + (size_t)v * 64 + li * 8 + 0) = o0;
        *(float4*)(out + (size_t)v * 64 + li * 8 + 4) = o1;
    }
}

// ---------------------------------------------------------------------------
// Fused mean-pool + MLP head: one block per graph.
// ---------------------------------------------------------------------------
__global__ __launch_bounds__(256)
void k_pool_mlp(const float* __restrict__ out2, const int* __restrict__ batch,
                const float* __restrict__ fc1w, const float* __restrict__ fc1b,
                const float* __restrict__ fc2w, const float* __restrict__ fc2b,
                const float* __restrict__ fcw,  const float* __restrict__ fcb,
                float* __restrict__ outc, float* __restrict__ outx2, int n) {
    const int g = blockIdx.x;
    const int t = threadIdx.x;
    const int lane = t & 63;
    const int w = t >> 6;
    __shared__ float red[4][64];
    __shared__ float hg_s[64];
    __shared__ float x1_s[32];
    __shared__ float x2_s[16];

    int lo = 0, hi = n;
    while (lo < hi) { int mid = (lo + hi) >> 1; if (batch[mid] < g) lo = mid + 1; else hi = mid; }
    const int start = lo;
    hi = n;
    while (lo < hi) { int mid = (lo + hi) >> 1; if (batch[mid] < g + 1) lo = mid + 1; else hi = mid; }
    const int end = lo;

    float s = 0.f;
    for (int v = start + w; v < end; v += 4)
        s += out2[(size_t)v * 64 + lane];
    red[w][lane] = s;
    __syncthreads();
    if (w == 0) {
        float tot = red[0][lane] + red[1][lane] + red[2][lane] + red[3][lane];
        float cnt = fmaxf((float)(end - start), 1.0f);
        hg_s[lane] = tot / cnt;
    }
    __syncthreads();
    if (t < 32) {
        float a = fc1b[t];
        #pragma unroll
        for (int k = 0; k < 64; ++k) a = fmaf(hg_s[k], fc1w[k * 32 + t], a);
        x1_s[t] = fmaxf(a, 0.f);
    }
    __syncthreads();
    if (t < 16) {
        float a = fc2b[t];
        #pragma unroll
        for (int k = 0; k < 32; ++k) a = fmaf(x1_s[k], fc2w[k * 16 + t], a);
        x2_s[t] = fmaxf(a, 0.f);
    }
    __syncthreads();
    if (t < DOUT) {
        float a = fcb[t];
        #pragma unroll
        for (int k = 0; k < 16; ++k) a = fmaf(x2_s[k], fcw[k * 10 + t], a);
        outc[g * DOUT + t] = a;
    }
    if (t < 16) outx2[g * 16 + t] = x2_s[t];
}

// ---------------------------------------------------------------------------
extern "C" void kernel_launch(void* const* d_in, const int* in_sizes, int n_in,
                              void* d_out, int out_size, void* d_ws, size_t ws_size,
                              hipStream_t stream) {
    const float* x    = (const float*)d_in[0];
    const int*   ei   = (const int*)d_in[1];
    const int*   batch= (const int*)d_in[2];
    const float* W1l  = (const float*)d_in[3];
    const float* W1r  = (const float*)d_in[4];
    const float* a1   = (const float*)d_in[5];
    const float* b1   = (const float*)d_in[6];
    const float* W2l  = (const float*)d_in[7];
    const float* W2r  = (const float*)d_in[8];
    const float* a2   = (const float*)d_in[9];
    const float* b2   = (const float*)d_in[10];
    const float* fc1w = (const float*)d_in[11];
    const float* fc1b = (const float*)d_in[12];
    const float* fc2w = (const float*)d_in[13];
    const float* fc2b = (const float*)d_in[14];
    const float* fcw  = (const float*)d_in[15];
    const float* fcb  = (const float*)d_in[16];

    const int N = in_sizes[2];          // 30000
    const int E = in_sizes[1] / 2;      // 480000
    const int ET = E + N;
    const int* esrc = ei;
    const int* edst = ei + E;
    const int NB = (N + SCAN_B - 1) / SCAN_B;   // 59 (<=64)

    // workspace layout
    char* ws = (char*)d_ws;
    size_t off = 0;
    unsigned short* xl1b = (unsigned short*)(ws + off);  off += (size_t)N * 256 * 2;
    float* xr1  = (float*)(ws + off);            off += (size_t)N * 256 * 4;
    unsigned short* h1b = (unsigned short*)(ws + off);   off += (size_t)N * 256 * 2;
    int*   deg   = (int*)(ws + off);             off += ((size_t)(N + 1) * 4 + 255) & ~255ull;
    int*   cursor= (int*)(ws + off);             off += ((size_t)N * 4 + 255) & ~255ull;
    int*   csr   = (int*)(ws + off);             off += ((size_t)ET * 4 + 255) & ~255ull;
    int*   bsum  = (int*)(ws + off);             off += ((size_t)(NB + 1) * 4 + 255) & ~255ull;
    short* B1th  = (short*)(ws + off);           off += (size_t)512 * 128 * 2;
    short* B1tl  = (short*)(ws + off);           off += (size_t)512 * 128 * 2;
    short* B2th  = (short*)(ws + off);           off += (size_t)128 * 256 * 2;
    short* B2tl  = (short*)(ws + off);           off += (size_t)128 * 256 * 2;
    unsigned short* xl2b = xl1b;                 // [N,64] bf16 (reuse)
    float* xr2  = xr1;                           // [N,64] f32 (reuse)
    float* out2 = xr1 + (size_t)N * 64;          // [N,64] f32
    (void)ws_size; (void)n_in; (void)out_size;

    float* outc  = (float*)d_out;
    float* outx2 = (float*)d_out + GNUM * DOUT;

    // Prep: zero deg + split weights
    const int prep_tot = 512 * 128 + 128 * 256;
    k_prep<<<(prep_tot + 255) / 256, 256, 0, stream>>>(
        W1l, W1r, W2l, W2r, B1th, B1tl, B2th, B2tl, deg, N + 1);

    // CSR build
    int tb = 256;
    int gb = (ET + tb - 1) / tb;
    k_deg<<<gb, tb, 0, stream>>>(edst, deg, E, N);
    k_scan_partial<<<NB, SCAN_B, 0, stream>>>(deg, bsum, N);
    k_scan_apply<<<NB, SCAN_B, 0, stream>>>(deg, cursor, bsum, N, NB);
    k_scatter<<<gb, tb, 0, stream>>>(esrc, edst, cursor, csr, E, N);

    // Layer 1 GEMM (64x128 tiles, 1876 blocks): cols 0..255 -> xl1b, 256..511 -> xr1
    dim3 g1((N + 63) / 64, 4);
    k_gemm1<<<g1, 256, 0, stream>>>(x, B1th, B1tl, xl1b, xr1, N, DIN, 512, 256);

    // Layer 1 edge pass (2 edges/load) -> h1b bf16
    k_edge1<<<N, 64, 0, stream>>>(xl1b, xr1, deg, csr, a1, b1, h1b, N);

    // Layer 2 GEMM (32x128 tiles, 938 blocks): cols 0..63 -> xl2b, 64..127 -> xr2
    dim3 g2((N + 31) / 32, 1);
    k_gemm_bf<<<g2, 256, 0, stream>>>(h1b, B2th, B2tl, xl2b, xr2, N, 256, 128, 64);

    // Layer 2 edge pass (8 edges/load) -> out2
    k_edge2<<<N, 64, 0, stream>>>(xl2b, xr2, deg, csr, a2, b2, out2, N);

    // Fused pool + MLP
    k_pool_mlp<<<GNUM, 256, 0, stream>>>(out2, batch, fc1w, fc1b, fc2w, fc2b,
                                         fcw, fcb, outc, outx2, N);
}

// Round 17
// 294.505 us; speedup vs baseline: 1.0249x; 1.0249x over previous
//
#include <hip/hip_runtime.h>
#include <math.h>

#define DIN 128
#define DH  32
#define H1  8
#define H2  2
#define GNUM 64
#define DOUT 10
#define NEG_SLOPE 0.2f
#define SCAN_B 512

typedef __attribute__((ext_vector_type(8))) short sv8;
typedef __attribute__((ext_vector_type(4))) short sv4;
typedef __attribute__((ext_vector_type(4))) float fv4;

static __device__ __forceinline__ unsigned short f2bf(float f) {
    unsigned int u = __float_as_uint(f);
    unsigned int r = (u + 0x7fffu + ((u >> 16) & 1u)) >> 16;
    return (unsigned short)r;
}
static __device__ __forceinline__ float bf2f(unsigned short h) {
    return __uint_as_float(((unsigned int)h) << 16);
}

// ---------------------------------------------------------------------------
// Prep: zero deg, transpose+split W1/W2 (small)
// ---------------------------------------------------------------------------
__global__ void k_prep(const float* __restrict__ W1l, const float* __restrict__ W1r,
                       const float* __restrict__ W2l, const float* __restrict__ W2r,
                       short* __restrict__ B1th, short* __restrict__ B1tl,
                       short* __restrict__ B2th, short* __restrict__ B2tl,
                       int* __restrict__ zbase, int nz) {
    int id = blockIdx.x * blockDim.x + threadIdx.x;
    if (id < nz) zbase[id] = 0;        // deg[N+1]
    const int T1 = 512 * 128;
    const int T2 = 128 * 256;
    if (id < T1) {
        int n = id / 128, k = id - n * 128;
        float v = (n < 256) ? W1l[(size_t)k * 256 + n] : W1r[(size_t)k * 256 + (n - 256)];
        unsigned short h = f2bf(v);
        B1th[id] = (short)h;
        B1tl[id] = (short)f2bf(v - bf2f(h));
    } else if (id < T1 + T2) {
        int id2 = id - T1;
        int n = id2 / 256, k = id2 - n * 256;
        float v = (n < 64) ? W2l[(size_t)k * 64 + n] : W2r[(size_t)k * 64 + (n - 64)];
        unsigned short h = f2bf(v);
        B2th[id2] = (short)h;
        B2tl[id2] = (short)f2bf(v - bf2f(h));
    }
}

// ---------------------------------------------------------------------------
// CSR build
// ---------------------------------------------------------------------------
__global__ void k_deg(const int* __restrict__ dst, int* __restrict__ deg, int E, int n) {
    int i = blockIdx.x * blockDim.x + threadIdx.x;
    if (i < E) {
        atomicAdd(&deg[dst[i]], 1);
    } else if (i < E + n) {
        atomicAdd(&deg[i - E], 1);   // self loop
    }
}

__global__ __launch_bounds__(SCAN_B)
void k_scan_partial(const int* __restrict__ deg, int* __restrict__ bsum, int n) {
    int i = blockIdx.x * SCAN_B + threadIdx.x;
    int v = (i < n) ? deg[i] : 0;
    #pragma unroll
    for (int m = 32; m >= 1; m >>= 1) v += __shfl_xor(v, m);
    __shared__ int red[SCAN_B / 64];
    if ((threadIdx.x & 63) == 0) red[threadIdx.x >> 6] = v;
    __syncthreads();
    if (threadIdx.x == 0) {
        int s = 0;
        #pragma unroll
        for (int k = 0; k < SCAN_B / 64; ++k) s += red[k];
        bsum[blockIdx.x] = s;
    }
}

// scan_apply with inlined block-prefix (nb <= 64)
__global__ __launch_bounds__(SCAN_B)
void k_scan_apply(int* __restrict__ deg, int* __restrict__ cursor,
                  const int* __restrict__ bsum, int n, int nb) {
    __shared__ int buf[SCAN_B];
    __shared__ int pfx_s, tot_s;
    const int t = threadIdx.x, b = blockIdx.x;
    if (t < 64) {
        int v = (t < nb) ? bsum[t] : 0;
        int incl = v;
        #pragma unroll
        for (int o = 1; o < 64; o <<= 1) {
            int w = __shfl_up(incl, o);
            if (t >= o) incl += w;
        }
        int pfx = (b == 0) ? 0 : __shfl(incl, b - 1);
        int tot = __shfl(incl, nb - 1);
        if (t == 0) { pfx_s = pfx; tot_s = tot; }
    }
    int i = b * SCAN_B + t;
    int v = (i < n) ? deg[i] : 0;
    buf[t] = v;
    __syncthreads();
    for (int o = 1; o < SCAN_B; o <<= 1) {
        int a = (t >= o) ? buf[t - o] : 0;
        __syncthreads();
        buf[t] += a;
        __syncthreads();
    }
    int excl = buf[t] - v + pfx_s;
    if (i < n) { deg[i] = excl; cursor[i] = excl; }
    if (b == 0 && t == 0) deg[n] = tot_s;
}

__global__ void k_scatter(const int* __restrict__ src, const int* __restrict__ dst,
                          int* __restrict__ cursor, int* __restrict__ csr_src, int E, int n) {
    int i = blockIdx.x * blockDim.x + threadIdx.x;
    if (i < E) {
        int d = dst[i];
        int pos = atomicAdd(&cursor[d], 1);
        csr_src[pos] = src[i];
    } else if (i < E + n) {
        int v = i - E;
        int pos = atomicAdd(&cursor[v], 1);
        csr_src[pos] = v;   // self loop
    }
}

// ---------------------------------------------------------------------------
// Layer-1 GEMM: 128x128 tile, A f32 -> bf16 hi/lo on the fly, 3 products,
// ALL outputs bf16 -> C[N,512] (halves the write traffic vs f32 xr).
// Slim 64x64-slice epilogue; LDS = 20.5 KB.
// ---------------------------------------------------------------------------
__global__ __launch_bounds__(256)
void k_gemm1(const float* __restrict__ A,
             const short* __restrict__ Bth, const short* __restrict__ Btl,
             unsigned short* __restrict__ C,
             int M, int K, int Ntot) {
    __shared__ union {
        struct { short hi[128 * 40]; short lo[128 * 40]; } a;   // 20480 B
        float c[64 * 68];                                        // 17408 B
    } sm;
    const int tid = threadIdx.x;
    const int lane = tid & 63;
    const int wid = tid >> 6;
    const int wm = wid & 1, wn = wid >> 1;
    const int m0 = blockIdx.x * 128;
    const int n0 = blockIdx.y * 128;
    const int l15 = lane & 15, q = lane >> 4;

    fv4 acc[4][4] = {};

    for (int kk = 0; kk < K; kk += 32) {
        __syncthreads();
        #pragma unroll
        for (int i = 0; i < 4; ++i) {
            int idx = tid + i * 256;      // 1024 float4 slots
            int row = idx >> 3;
            int qq  = idx & 7;
            int mg  = m0 + row;
            float4 v = make_float4(0.f, 0.f, 0.f, 0.f);
            if (mg < M) v = *(const float4*)(A + (size_t)mg * K + kk + qq * 4);
            unsigned short hx = f2bf(v.x), hy = f2bf(v.y), hz = f2bf(v.z), hw = f2bf(v.w);
            sv4 hi = { (short)hx, (short)hy, (short)hz, (short)hw };
            sv4 lo = { (short)f2bf(v.x - bf2f(hx)), (short)f2bf(v.y - bf2f(hy)),
                       (short)f2bf(v.z - bf2f(hz)), (short)f2bf(v.w - bf2f(hw)) };
            *(sv4*)&sm.a.hi[row * 40 + qq * 4] = hi;
            *(sv4*)&sm.a.lo[row * 40 + qq * 4] = lo;
        }
        __syncthreads();

        sv8 bh[4], bl[4];
        #pragma unroll
        for (int fn = 0; fn < 4; ++fn) {
            int ng = n0 + wn * 64 + fn * 16 + l15;
            bh[fn] = *(const sv8*)(Bth + (size_t)ng * K + kk + q * 8);
            bl[fn] = *(const sv8*)(Btl + (size_t)ng * K + kk + q * 8);
        }
        #pragma unroll
        for (int fm = 0; fm < 4; ++fm) {
            int rl = wm * 64 + fm * 16 + l15;
            sv8 ah = *(const sv8*)&sm.a.hi[rl * 40 + q * 8];
            sv8 al = *(const sv8*)&sm.a.lo[rl * 40 + q * 8];
            #pragma unroll
            for (int fn = 0; fn < 4; ++fn) {
                acc[fm][fn] = __builtin_amdgcn_mfma_f32_16x16x32_bf16(ah, bh[fn], acc[fm][fn], 0, 0, 0);
                acc[fm][fn] = __builtin_amdgcn_mfma_f32_16x16x32_bf16(ah, bl[fn], acc[fm][fn], 0, 0, 0);
                acc[fm][fn] = __builtin_amdgcn_mfma_f32_16x16x32_bf16(al, bh[fn], acc[fm][fn], 0, 0, 0);
            }
        }
    }

    // epilogue: 4 slices (row-half s x col-half cn), 64x64 each, bf16 only
    #pragma unroll
    for (int s = 0; s < 2; ++s) {
        #pragma unroll
        for (int cn = 0; cn < 2; ++cn) {
            __syncthreads();
            if (wm == s && wn == cn) {
                #pragma unroll
                for (int fm = 0; fm < 4; ++fm)
                    #pragma unroll
                    for (int fn = 0; fn < 4; ++fn)
                        #pragma unroll
                        for (int r = 0; r < 4; ++r)
                            sm.c[(fm * 16 + q * 4 + r) * 68 + fn * 16 + l15] = acc[fm][fn][r];
            }
            __syncthreads();
            int lr = tid >> 2;              // 0..63
            int grow = m0 + s * 64 + lr;
            if (grow < M) {
                #pragma unroll
                for (int k4 = 0; k4 < 4; ++k4) {
                    int jj = (tid & 3) + k4 * 4;    // 0..15 float4 index
                    float4 vv = *(float4*)&sm.c[lr * 68 + jj * 4];
                    int gcol = n0 + cn * 64 + jj * 4;
                    ushort4 uu;
                    uu.x = f2bf(vv.x); uu.y = f2bf(vv.y);
                    uu.z = f2bf(vv.z); uu.w = f2bf(vv.w);
                    *(ushort4*)(C + (size_t)grow * Ntot + gcol) = uu;
                }
            }
        }
    }
}

// ---------------------------------------------------------------------------
// Layer-2 GEMM: A bf16 (h1b), 2 products, 128x128 tile, all-bf16 output.
// ---------------------------------------------------------------------------
__global__ __launch_bounds__(256)
void k_gemm_bf(const unsigned short* __restrict__ A, const short* __restrict__ Bth,
               const short* __restrict__ Btl,
               unsigned short* __restrict__ C,
               int M, int K, int Ntot) {
    __shared__ union {
        short a[128 * 40];
        float c[64 * 68];
    } sm;
    const int tid = threadIdx.x;
    const int lane = tid & 63;
    const int wid = tid >> 6;
    const int wm = wid & 1, wn = wid >> 1;
    const int m0 = blockIdx.x * 128;
    const int n0 = blockIdx.y * 128;
    const int l15 = lane & 15, q = lane >> 4;

    fv4 acc[4][4] = {};

    for (int kk = 0; kk < K; kk += 32) {
        __syncthreads();
        #pragma unroll
        for (int i = 0; i < 2; ++i) {
            int idx = tid + i * 256;
            int row = idx >> 2, qq = idx & 3;
            int mg = m0 + row;
            sv8 v = { 0, 0, 0, 0, 0, 0, 0, 0 };
            if (mg < M) v = *(const sv8*)(A + (size_t)mg * K + kk + qq * 8);
            *(sv8*)&sm.a[row * 40 + qq * 8] = v;
        }
        __syncthreads();

        sv8 bh[4], bl[4];
        #pragma unroll
        for (int fn = 0; fn < 4; ++fn) {
            int ng = n0 + wn * 64 + fn * 16 + l15;
            bh[fn] = *(const sv8*)(Bth + (size_t)ng * K + kk + q * 8);
            bl[fn] = *(const sv8*)(Btl + (size_t)ng * K + kk + q * 8);
        }
        #pragma unroll
        for (int fm = 0; fm < 4; ++fm) {
            int rl = wm * 64 + fm * 16 + l15;
            sv8 ah = *(const sv8*)&sm.a[rl * 40 + q * 8];
            #pragma unroll
            for (int fn = 0; fn < 4; ++fn) {
                acc[fm][fn] = __builtin_amdgcn_mfma_f32_16x16x32_bf16(ah, bh[fn], acc[fm][fn], 0, 0, 0);
                acc[fm][fn] = __builtin_amdgcn_mfma_f32_16x16x32_bf16(ah, bl[fn], acc[fm][fn], 0, 0, 0);
            }
        }
    }

    #pragma unroll
    for (int s = 0; s < 2; ++s) {
        #pragma unroll
        for (int cn = 0; cn < 2; ++cn) {
            __syncthreads();
            if (wm == s && wn == cn) {
                #pragma unroll
                for (int fm = 0; fm < 4; ++fm)
                    #pragma unroll
                    for (int fn = 0; fn < 4; ++fn)
                        #pragma unroll
                        for (int r = 0; r < 4; ++r)
                            sm.c[(fm * 16 + q * 4 + r) * 68 + fn * 16 + l15] = acc[fm][fn][r];
            }
            __syncthreads();
            int lr = tid >> 2;
            int grow = m0 + s * 64 + lr;
            if (grow < M) {
                #pragma unroll
                for (int k4 = 0; k4 < 4; ++k4) {
                    int jj = (tid & 3) + k4 * 4;
                    float4 vv = *(float4*)&sm.c[lr * 68 + jj * 4];
                    int gcol = n0 + cn * 64 + jj * 4;
                    ushort4 uu;
                    uu.x = f2bf(vv.x); uu.y = f2bf(vv.y);
                    uu.z = f2bf(vv.z); uu.w = f2bf(vv.w);
                    *(ushort4*)(C + (size_t)grow * Ntot + gcol) = uu;
                }
            }
        }
    }
}

// ---------------------------------------------------------------------------
// Layer-1 edge pass: one wave per block. XLR[N,512] bf16: cols 0..255 = xl,
// 256..511 = xr. lane li (0..31) owns 8 ch; half = edge slot.
// ---------------------------------------------------------------------------
__global__ __launch_bounds__(64)
void k_edge1(const unsigned short* __restrict__ XLR,
             const int* __restrict__ offs, const int* __restrict__ csr,
             const float* __restrict__ att, const float* __restrict__ bias,
             unsigned short* __restrict__ out, int n) {
    const int lane = threadIdx.x;
    const int v = blockIdx.x;
    const int li = lane & 31;
    const int half = lane >> 5;
    const uint4* XL4 = (const uint4*)XLR;   // row = 64 uint4 (512 bf16)
    float av[8], xr[8];
    #pragma unroll
    for (int k = 0; k < 8; ++k) av[k] = att[li * 8 + k];
    {
        uint4 u = XL4[(size_t)v * 64 + 32 + li];
        xr[0] = __uint_as_float(u.x << 16);  xr[1] = __uint_as_float(u.x & 0xffff0000u);
        xr[2] = __uint_as_float(u.y << 16);  xr[3] = __uint_as_float(u.y & 0xffff0000u);
        xr[4] = __uint_as_float(u.z << 16);  xr[5] = __uint_as_float(u.z & 0xffff0000u);
        xr[6] = __uint_as_float(u.w << 16);  xr[7] = __uint_as_float(u.w & 0xffff0000u);
    }
    float z = 0.f;
    float acc[8] = {};
    const int e0 = offs[v], e1 = offs[v + 1];
    for (int j0 = e0; j0 < e1; j0 += 4) {
        #pragma unroll
        for (int p = 0; p < 2; ++p) {
            int j = j0 + p * 2 + half;
            bool valid = (j < e1);
            int jj = valid ? j : (e1 - 1);
            int src = csr[jj];
            uint4 u = XL4[(size_t)src * 64 + li];
            float f[8];
            f[0] = __uint_as_float(u.x << 16);  f[1] = __uint_as_float(u.x & 0xffff0000u);
            f[2] = __uint_as_float(u.y << 16);  f[3] = __uint_as_float(u.y & 0xffff0000u);
            f[4] = __uint_as_float(u.z << 16);  f[5] = __uint_as_float(u.z & 0xffff0000u);
            f[6] = __uint_as_float(u.w << 16);  f[7] = __uint_as_float(u.w & 0xffff0000u);
            float s1 = 0.f, s2 = 0.f;
            #pragma unroll
            for (int k = 0; k < 8; ++k) {
                float t = f[k] + xr[k];
                s1 = fmaf(t, av[k], s1);
                s2 = fmaf(fabsf(t), av[k], s2);
            }
            float s = fmaf(0.6f, s1, 0.4f * s2);
            s += __shfl_xor(s, 1);
            s += __shfl_xor(s, 2);
            float w = valid ? __expf(s) : 0.f;
            z += w;
            #pragma unroll
            for (int k = 0; k < 8; ++k) acc[k] = fmaf(w, f[k], acc[k]);
        }
    }
    z += __shfl_xor(z, 32);
    #pragma unroll
    for (int k = 0; k < 8; ++k) acc[k] += __shfl_xor(acc[k], 32);
    if (half == 0) {
        const float rz = 1.f / z;
        unsigned int o[4];
        #pragma unroll
        for (int k2 = 0; k2 < 4; ++k2) {
            float lo = fmaf(acc[k2 * 2 + 0], rz, bias[li * 8 + k2 * 2 + 0]);
            float hi = fmaf(acc[k2 * 2 + 1], rz, bias[li * 8 + k2 * 2 + 1]);
            lo = (lo > 0.f) ? lo : (__expf(lo) - 1.f);
            hi = (hi > 0.f) ? hi : (__expf(hi) - 1.f);
            o[k2] = (unsigned int)f2bf(lo) | ((unsigned int)f2bf(hi) << 16);
        }
        uint4 ov = { o[0], o[1], o[2], o[3] };
        *(uint4*)(out + (size_t)v * 256 + li * 8) = ov;
    }
}

// ---------------------------------------------------------------------------
// Layer-2 edge pass: one wave per block. XLR[N,128] bf16: cols 0..63 = xl,
// 64..127 = xr. lane li (0..7) owns 8 ch; slot = lane>>3.
// ---------------------------------------------------------------------------
__global__ __launch_bounds__(64)
void k_edge2(const unsigned short* __restrict__ XLR,
             const int* __restrict__ offs, const int* __restrict__ csr,
             const float* __restrict__ att, const float* __restrict__ bias,
             float* __restrict__ out, int n) {
    const int lane = threadIdx.x;
    const int v = blockIdx.x;
    const int li = lane & 7;
    const int slot = lane >> 3;
    const uint4* XL4 = (const uint4*)XLR;   // row = 16 uint4 (128 bf16)
    float av[8], xr[8];
    #pragma unroll
    for (int k = 0; k < 8; ++k) av[k] = att[li * 8 + k];
    {
        uint4 u = XL4[(size_t)v * 16 + 8 + li];
        xr[0] = __uint_as_float(u.x << 16);  xr[1] = __uint_as_float(u.x & 0xffff0000u);
        xr[2] = __uint_as_float(u.y << 16);  xr[3] = __uint_as_float(u.y & 0xffff0000u);
        xr[4] = __uint_as_float(u.z << 16);  xr[5] = __uint_as_float(u.z & 0xffff0000u);
        xr[6] = __uint_as_float(u.w << 16);  xr[7] = __uint_as_float(u.w & 0xffff0000u);
    }
    float z = 0.f;
    float acc[8] = {};
    const int e0 = offs[v], e1 = offs[v + 1];
    for (int j0 = e0; j0 < e1; j0 += 8) {
        int j = j0 + slot;
        bool valid = (j < e1);
        int jj = valid ? j : (e1 - 1);
        int src = csr[jj];
        uint4 u = XL4[(size_t)src * 16 + li];
        float f[8];
        f[0] = __uint_as_float(u.x << 16);  f[1] = __uint_as_float(u.x & 0xffff0000u);
        f[2] = __uint_as_float(u.y << 16);  f[3] = __uint_as_float(u.y & 0xffff0000u);
        f[4] = __uint_as_float(u.z << 16);  f[5] = __uint_as_float(u.z & 0xffff0000u);
        f[6] = __uint_as_float(u.w << 16);  f[7] = __uint_as_float(u.w & 0xffff0000u);
        float s1 = 0.f, s2 = 0.f;
        #pragma unroll
        for (int k = 0; k < 8; ++k) {
            float t = f[k] + xr[k];
            s1 = fmaf(t, av[k], s1);
            s2 = fmaf(fabsf(t), av[k], s2);
        }
        float s = fmaf(0.6f, s1, 0.4f * s2);
        s += __shfl_xor(s, 1);
        s += __shfl_xor(s, 2);
        float w = valid ? __expf(s) : 0.f;
        z += w;
        #pragma unroll
        for (int k = 0; k < 8; ++k) acc[k] = fmaf(w, f[k], acc[k]);
    }
    z += __shfl_xor(z, 8);  z += __shfl_xor(z, 16);  z += __shfl_xor(z, 32);
    #pragma unroll
    for (int k = 0; k < 8; ++k) {
        acc[k] += __shfl_xor(acc[k], 8);
        acc[k] += __shfl_xor(acc[k], 16);
        acc[k] += __shfl_xor(acc[k], 32);
    }
    if (slot == 0) {
        const float rz = 1.f / z;
        float o[8];
        #pragma unroll
        for (int k = 0; k < 8; ++k)
            o[k] = fmaf(acc[k], rz, bias[li * 8 + k]);
        float4 o0 = { o[0], o[1], o[2], o[3] };
        float4 o1 = { o[4], o[5], o[6], o[7] };
        *(float4*)(out + (size_t)v * 64 + li * 8 + 0) = o0;
        *(float4*)(out + (size_t)v * 64 + li * 8 + 4) = o1;
    }
}

// ---------------------------------------------------------------------------
// Fused mean-pool + MLP head: one block per graph.
// ---------------------------------------------------------------------------
__global__ __launch_bounds__(256)
void k_pool_mlp(const float* __restrict__ out2, const int* __restrict__ batch,
                const float* __restrict__ fc1w, const float* __restrict__ fc1b,
                const float* __restrict__ fc2w, const float* __restrict__ fc2b,
                const float* __restrict__ fcw,  const float* __restrict__ fcb,
                float* __restrict__ outc, float* __restrict__ outx2, int n) {
    const int g = blockIdx.x;
    const int t = threadIdx.x;
    const int lane = t & 63;
    const int w = t >> 6;
    __shared__ float red[4][64];
    __shared__ float hg_s[64];
    __shared__ float x1_s[32];
    __shared__ float x2_s[16];

    int lo = 0, hi = n;
    while (lo < hi) { int mid = (lo + hi) >> 1; if (batch[mid] < g) lo = mid + 1; else hi = mid; }
    const int start = lo;
    hi = n;
    while (lo < hi) { int mid = (lo + hi) >> 1; if (batch[mid] < g + 1) lo = mid + 1; else hi = mid; }
    const int end = lo;

    float s = 0.f;
    for (int v = start + w; v < end; v += 4)
        s += out2[(size_t)v * 64 + lane];
    red[w][lane] = s;
    __syncthreads();
    if (w == 0) {
        float tot = red[0][lane] + red[1][lane] + red[2][lane] + red[3][lane];
        float cnt = fmaxf((float)(end - start), 1.0f);
        hg_s[lane] = tot / cnt;
    }
    __syncthreads();
    if (t < 32) {
        float a = fc1b[t];
        #pragma unroll
        for (int k = 0; k < 64; ++k) a = fmaf(hg_s[k], fc1w[k * 32 + t], a);
        x1_s[t] = fmaxf(a, 0.f);
    }
    __syncthreads();
    if (t < 16) {
        float a = fc2b[t];
        #pragma unroll
        for (int k = 0; k < 32; ++k) a = fmaf(x1_s[k], fc2w[k * 16 + t], a);
        x2_s[t] = fmaxf(a, 0.f);
    }
    __syncthreads();
    if (t < DOUT) {
        float a = fcb[t];
        #pragma unroll
        for (int k = 0; k < 16; ++k) a = fmaf(x2_s[k], fcw[k * 10 + t], a);
        outc[g * DOUT + t] = a;
    }
    if (t < 16) outx2[g * 16 + t] = x2_s[t];
}

// ---------------------------------------------------------------------------
extern "C" void kernel_launch(void* const* d_in, const int* in_sizes, int n_in,
                              void* d_out, int out_size, void* d_ws, size_t ws_size,
                              hipStream_t stream) {
    const float* x    = (const float*)d_in[0];
    const int*   ei   = (const int*)d_in[1];
    const int*   batch= (const int*)d_in[2];
    const float* W1l  = (const float*)d_in[3];
    const float* W1r  = (const float*)d_in[4];
    const float* a1   = (const float*)d_in[5];
    const float* b1   = (const float*)d_in[6];
    const float* W2l  = (const float*)d_in[7];
    const float* W2r  = (const float*)d_in[8];
    const float* a2   = (const float*)d_in[9];
    const float* b2   = (const float*)d_in[10];
    const float* fc1w = (const float*)d_in[11];
    const float* fc1b = (const float*)d_in[12];
    const float* fc2w = (const float*)d_in[13];
    const float* fc2b = (const float*)d_in[14];
    const float* fcw  = (const float*)d_in[15];
    const float* fcb  = (const float*)d_in[16];

    const int N = in_sizes[2];          // 30000
    const int E = in_sizes[1] / 2;      // 480000
    const int ET = E + N;
    const int* esrc = ei;
    const int* edst = ei + E;
    const int NB = (N + SCAN_B - 1) / SCAN_B;   // 59 (<=64)

    // workspace layout
    char* ws = (char*)d_ws;
    size_t off = 0;
    unsigned short* xlr1b = (unsigned short*)(ws + off); off += (size_t)N * 512 * 2;  // [N,512] xl|xr bf16
    unsigned short* h1b  = (unsigned short*)(ws + off);  off += (size_t)N * 256 * 2;  // [N,256] bf16
    float* out2 = (float*)(ws + off);            off += (size_t)N * 64 * 4;           // [N,64] f32
    int*   deg   = (int*)(ws + off);             off += ((size_t)(N + 1) * 4 + 255) & ~255ull;
    int*   cursor= (int*)(ws + off);             off += ((size_t)N * 4 + 255) & ~255ull;
    int*   csr   = (int*)(ws + off);             off += ((size_t)ET * 4 + 255) & ~255ull;
    int*   bsum  = (int*)(ws + off);             off += ((size_t)(NB + 1) * 4 + 255) & ~255ull;
    short* B1th  = (short*)(ws + off);           off += (size_t)512 * 128 * 2;
    short* B1tl  = (short*)(ws + off);           off += (size_t)512 * 128 * 2;
    short* B2th  = (short*)(ws + off);           off += (size_t)128 * 256 * 2;
    short* B2tl  = (short*)(ws + off);           off += (size_t)128 * 256 * 2;
    unsigned short* xlr2b = xlr1b;               // [N,128] bf16 (reuse)
    (void)ws_size; (void)n_in; (void)out_size;

    float* outc  = (float*)d_out;
    float* outx2 = (float*)d_out + GNUM * DOUT;

    // Prep: zero deg + split weights
    const int prep_tot = 512 * 128 + 128 * 256;
    k_prep<<<(prep_tot + 255) / 256, 256, 0, stream>>>(
        W1l, W1r, W2l, W2r, B1th, B1tl, B2th, B2tl, deg, N + 1);

    // CSR build
    int tb = 256;
    int gb = (ET + tb - 1) / tb;
    k_deg<<<gb, tb, 0, stream>>>(edst, deg, E, N);
    k_scan_partial<<<NB, SCAN_B, 0, stream>>>(deg, bsum, N);
    k_scan_apply<<<NB, SCAN_B, 0, stream>>>(deg, cursor, bsum, N, NB);
    k_scatter<<<gb, tb, 0, stream>>>(esrc, edst, cursor, csr, E, N);

    // Layer 1 GEMM (all-bf16 output): xlr1b[N,512]
    dim3 g1((N + 127) / 128, 4);
    k_gemm1<<<g1, 256, 0, stream>>>(x, B1th, B1tl, xlr1b, N, DIN, 512);

    // Layer 1 edge pass -> h1b bf16
    k_edge1<<<N, 64, 0, stream>>>(xlr1b, deg, csr, a1, b1, h1b, N);

    // Layer 2 GEMM (bf16 A, all-bf16 output): xlr2b[N,128]
    dim3 g2((N + 127) / 128, 1);
    k_gemm_bf<<<g2, 256, 0, stream>>>(h1b, B2th, B2tl, xlr2b, N, 256, 128);

    // Layer 2 edge pass -> out2 (f32)
    k_edge2<<<N, 64, 0, stream>>>(xlr2b, deg, csr, a2, b2, out2, N);

    // Fused pool + MLP
    k_pool_mlp<<<GNUM, 256, 0, stream>>>(out2, batch, fc1w, fc1b, fc2w, fc2b,
                                         fcw, fcb, outc, outx2, N);
}